// Round 12
// baseline (248.236 us; speedup 1.0000x reference)
//
#include <hip/hip_runtime.h>
#include <stdint.h>

typedef unsigned short u16;
typedef unsigned long long u64;
using short8 = __attribute__((ext_vector_type(8))) short;
using f32x16 = __attribute__((ext_vector_type(16))) float;
using f32x4v = __attribute__((ext_vector_type(4))) float;

#define NROWS 65536
#define DIM   512
#define KC    1024

#define GLOBAL_AS __attribute__((address_space(1)))
#define LDS_AS    __attribute__((address_space(3)))

__device__ __forceinline__ void gload_lds16(const void* g, void* l) {
  __builtin_amdgcn_global_load_lds((const GLOBAL_AS uint32_t*)g,
                                   (LDS_AS uint32_t*)l, 16, 0, 0);
}

__device__ __forceinline__ u16 f2bf(float f) {  // RNE float->bf16 bits
  unsigned u = __float_as_uint(f);
  return (u16)((u + 0x7fffu + ((u >> 16) & 1u)) >> 16);
}

__device__ __forceinline__ f32x4v ntload4(const float* p) {
  return __builtin_nontemporal_load((const f32x4v*)p);
}
__device__ __forceinline__ void ntstore4(float* p, f32x4v v) {
  __builtin_nontemporal_store(v, (f32x4v*)p);
}

// ---- W prep: W^T in MFMA-B-fragment order (32-code groups) + ||w||^2 ------
__global__ __launch_bounds__(256) void wprep_kernel(const float* __restrict__ W,
                                                    short8* __restrict__ WhT8,
                                                    float* __restrict__ wnorm,
                                                    int* __restrict__ counts,
                                                    double* __restrict__ sums) {
  if (blockIdx.x == 0) {
    for (int k = threadIdx.x; k < KC; k += 256) counts[k] = 0;
    if (threadIdx.x < 2) sums[threadIdx.x] = 0.0;
  }
  int code = blockIdx.x * 4 + (threadIdx.x >> 6);
  int l = threadIdx.x & 63;
  const float* wr = W + (size_t)code * DIM + l * 8;
  float4 v0 = *(const float4*)wr;
  float4 v1 = *(const float4*)(wr + 4);
  float s = v0.x * v0.x + v0.y * v0.y + v0.z * v0.z + v0.w * v0.w
          + v1.x * v1.x + v1.y * v1.y + v1.z * v1.z + v1.w * v1.w;
  short8 pk;
  pk[0] = (short)f2bf(v0.x); pk[1] = (short)f2bf(v0.y);
  pk[2] = (short)f2bf(v0.z); pk[3] = (short)f2bf(v0.w);
  pk[4] = (short)f2bf(v1.x); pk[5] = (short)f2bf(v1.y);
  pk[6] = (short)f2bf(v1.z); pk[7] = (short)f2bf(v1.w);
  WhT8[(size_t)(code >> 5) * 2048 + (l >> 1) * 64 + (l & 1) * 32 + (code & 31)] = pk;
#pragma unroll
  for (int off = 32; off; off >>= 1) s += __shfl_xor(s, off, 64);
  if (l == 0) wnorm[code] = s;
}

// ---- main fused kernel ----------------------------------------------------
// 256 thr = 4 waves x 64 rows = 256 rows/block, grid 256 = 1 block/CU,
// 1 wave/SIMD (512-reg budget). A: 2 row-panels in regs (256 VGPR). B: 64-code
// tiles double-buffered in LDS; each B-fragment ds_read feeds 2 MFMAs.
__global__ __launch_bounds__(256)
__attribute__((amdgpu_waves_per_eu(1, 1))) void mm_kernel(
    const float* __restrict__ X, const float* __restrict__ W,
    const u16* __restrict__ WhTf, const float* __restrict__ wnorm,
    int* __restrict__ counts, double* __restrict__ sums,
    float* __restrict__ out, float* __restrict__ encf) {
  __shared__ __align__(16) u16 BsU[2][32768];  // 2 x 64 KB (64-code tiles)
  __shared__ int rowk[256];
  __shared__ double sdbl[4];
  const int t = threadIdx.x;
  const int w = t >> 6, l = t & 63;
  const int r = l & 31, h = l >> 5;
  const int row0 = blockIdx.x * 256;

  // kick off tile 0 DMA (64 KB linear; wave-uniform dest + lane*16)
#pragma unroll
  for (int i = 0; i < 16; ++i)
    gload_lds16(WhTf + (i * 256 + t) * 8, &BsU[0][(i * 256 + t) * 8]);

  // A: 64 rows/wave in 2 panels of 32 -> regs as MFMA A-frags; fused sum(x^2)
  const float* Xr0 = X + (size_t)(row0 + w * 64 + r) * DIM + h * 8;
  const float* Xr1 = Xr0 + 32 * DIM;
  short8 aF0[32], aF1[32];
  double xacc = 0.0;
#pragma unroll
  for (int s = 0; s < 32; ++s) {
    f32x4v v0 = ntload4(Xr0 + s * 16);
    f32x4v v1 = ntload4(Xr0 + s * 16 + 4);
    f32x4v v2 = ntload4(Xr1 + s * 16);
    f32x4v v3 = ntload4(Xr1 + s * 16 + 4);
    xacc += (double)v0[0] * v0[0] + (double)v0[1] * v0[1] + (double)v0[2] * v0[2] + (double)v0[3] * v0[3]
          + (double)v1[0] * v1[0] + (double)v1[1] * v1[1] + (double)v1[2] * v1[2] + (double)v1[3] * v1[3]
          + (double)v2[0] * v2[0] + (double)v2[1] * v2[1] + (double)v2[2] * v2[2] + (double)v2[3] * v2[3]
          + (double)v3[0] * v3[0] + (double)v3[1] * v3[1] + (double)v3[2] * v3[2] + (double)v3[3] * v3[3];
    short8 p0, p1;
    p0[0] = (short)f2bf(v0[0]); p0[1] = (short)f2bf(v0[1]);
    p0[2] = (short)f2bf(v0[2]); p0[3] = (short)f2bf(v0[3]);
    p0[4] = (short)f2bf(v1[0]); p0[5] = (short)f2bf(v1[1]);
    p0[6] = (short)f2bf(v1[2]); p0[7] = (short)f2bf(v1[3]);
    p1[0] = (short)f2bf(v2[0]); p1[1] = (short)f2bf(v2[1]);
    p1[2] = (short)f2bf(v2[2]); p1[3] = (short)f2bf(v2[3]);
    p1[4] = (short)f2bf(v3[0]); p1[5] = (short)f2bf(v3[1]);
    p1[6] = (short)f2bf(v3[2]); p1[7] = (short)f2bf(v3[3]);
    aF0[s] = p0; aF1[s] = p1;
  }
#pragma unroll
  for (int off = 32; off; off >>= 1) xacc += __shfl_xor(xacc, off, 64);
  if (l == 0) atomicAdd(&sums[0], xacc);

  unsigned best_[32];
#pragma unroll
  for (int q = 0; q < 32; ++q) best_[q] = 0xFFFFFFFFu;

  f32x4v* encz = (f32x4v*)(encf + (size_t)row0 * KC);
  const f32x4v zero4 = {0.f, 0.f, 0.f, 0.f};

  asm volatile("s_waitcnt vmcnt(0)" ::: "memory");
  __builtin_amdgcn_s_barrier();
  __builtin_amdgcn_sched_barrier(0);

  for (int kt = 0; kt < 16; ++kt) {
    const int buf = kt & 1;
    if (kt < 15) {  // prefetch next 64-code tile (16 gloads, oldest)
      const u16* src = WhTf + (size_t)(kt + 1) * 32768;
#pragma unroll
      for (int i = 0; i < 16; ++i)
        gload_lds16(src + (i * 256 + t) * 8, &BsU[buf ^ 1][(i * 256 + t) * 8]);
    }
    // enc-zero NT stream (16 stores, newest; excluded from the drain)
#pragma unroll
    for (int i = 0; i < 16; ++i)
      __builtin_nontemporal_store(zero4, &encz[kt * 4096 + i * 256 + t]);

    const u16* bufp = &BsU[buf][l * 8];
#pragma unroll
    for (int cb = 0; cb < 2; ++cb) {
      f32x16 a0e = {}, a0o = {}, a1e = {}, a1o = {};
#pragma unroll
      for (int ks = 0; ks < 32; ++ks) {
        short8 bv = *(const short8*)&bufp[cb * 16384 + ks * 512];
        if (ks & 1) {
          a0o = __builtin_amdgcn_mfma_f32_32x32x16_bf16(aF0[ks], bv, a0o, 0, 0, 0);
          a1o = __builtin_amdgcn_mfma_f32_32x32x16_bf16(aF1[ks], bv, a1o, 0, 0, 0);
        } else {
          a0e = __builtin_amdgcn_mfma_f32_32x32x16_bf16(aF0[ks], bv, a0e, 0, 0, 0);
          a1e = __builtin_amdgcn_mfma_f32_32x32x16_bf16(aF1[ks], bv, a1e, 0, 0, 0);
        }
      }
      float wn = wnorm[kt * 64 + cb * 32 + r];
      unsigned col = (unsigned)(kt * 64 + cb * 32 + r);
#pragma unroll
      for (int q = 0; q < 16; ++q) {
        float s0 = fmaf(-2.0f, a0e[q] + a0o[q], wn);
        unsigned u0 = __float_as_uint(s0);
        unsigned k0 = (u0 & 0x80000000u) ? ~u0 : (u0 | 0x80000000u);
        best_[q] = min(best_[q], (k0 & 0xFFFFFC00u) | col);
        float s1 = fmaf(-2.0f, a1e[q] + a1o[q], wn);
        unsigned u1 = __float_as_uint(s1);
        unsigned k1 = (u1 & 0x80000000u) ? ~u1 : (u1 | 0x80000000u);
        best_[16 + q] = min(best_[16 + q], (k1 & 0xFFFFFC00u) | col);
      }
    }
    asm volatile("s_waitcnt vmcnt(16)" ::: "memory");  // gloads drained
    __builtin_amdgcn_s_barrier();
    __builtin_amdgcn_sched_barrier(0);
  }

  // per-row argmin across the 32 code-lanes; rowk + stats
  double local = 0.0;
#pragma unroll
  for (int q = 0; q < 32; ++q) {
    unsigned pb = best_[q];
#pragma unroll
    for (int off = 16; off; off >>= 1)
      pb = min(pb, (unsigned)__shfl_xor((int)pb, off, 32));
    if (r == 0) {
      int rit = w * 64 + (q >> 4) * 32 + (q & 3) + 8 * ((q >> 2) & 3) + 4 * h;
      int k = (int)(pb & 1023u);
      rowk[rit] = k;
      atomicAdd(&counts[k], 1);
      unsigned key = (pb & 0xFFFFFC00u) | 0x200u;  // midpoint reconstruction
      unsigned uu = (key & 0x80000000u) ? (key ^ 0x80000000u) : ~key;
      local += (double)__uint_as_float(uu);
    }
  }
  {
    double o32 = __shfl(local, 32, 64);
    if (l == 0) sdbl[w] = local + o32;
  }
  __syncthreads();  // rowk visible; all vm ops drained (zeros before ones)
  if (t == 0) atomicAdd(&sums[1], sdbl[0] + sdbl[1] + sdbl[2] + sdbl[3]);

  // fused quantized gather-write (aligned f4 NT around +1 base) + one-hot
  for (int j = 0; j < 64; ++j) {
    int rit = w * 64 + j;
    int k = rowk[rit];
    const float* Wr = W + (size_t)k * DIM;
    size_t ob = (size_t)(row0 + rit) * DIM;
    {
      f32x4v cm = *(const f32x4v*)(Wr + 4 * l);
      f32x4v c1 = *(const f32x4v*)(Wr + 4 * l + 4);
      f32x4v sv = {cm[3], c1[0], c1[1], c1[2]};
      ntstore4(out + ob + 4 + 4 * l, sv);
    }
    if (l <= 62) {
      int m = l + 64;
      f32x4v dm = *(const f32x4v*)(Wr + 4 * m);
      f32x4v d1 = *(const f32x4v*)(Wr + 4 * m + 4);
      f32x4v sv = {dm[3], d1[0], d1[1], d1[2]};
      ntstore4(out + ob + 4 + 4 * m, sv);
    }
    if (l < 3) out[ob + 1 + l] = Wr[l];        // head d=0,1,2
    if (l == 3) out[ob + 512] = Wr[511];       // tail d=511
    if (l == 4) encf[(size_t)(row0 + rit) * KC + k] = 1.0f;  // one-hot
  }
}

// ---- finalize: loss + perplexity ------------------------------------------
__global__ __launch_bounds__(256) void finalize_kernel(
    const int* __restrict__ counts, const double* __restrict__ sums,
    float* __restrict__ out_loss, float* __restrict__ out_perp) {
  __shared__ float red[4];
  int t = threadIdx.x;
  float h = 0.f;
  for (int k = t; k < KC; k += 256) {
    float p = (float)counts[k] / (float)NROWS;
    h -= p * logf(p + 1e-10f);
  }
#pragma unroll
  for (int off = 32; off; off >>= 1) h += __shfl_xor(h, off, 64);
  if ((t & 63) == 0) red[t >> 6] = h;
  __syncthreads();
  if (t == 0) {
    float H = red[0] + red[1] + red[2] + red[3];
    *out_perp = expf(H);
    double m = (sums[0] + sums[1]) / (double)((long long)NROWS * DIM);
    *out_loss = (float)(1.25 * m);
  }
}

extern "C" void kernel_launch(void* const* d_in, const int* in_sizes, int n_in,
                              void* d_out, int out_size, void* d_ws, size_t ws_size,
                              hipStream_t stream) {
  const float* X = (const float*)d_in[0];
  const float* W = (const float*)d_in[1];
  float* out = (float*)d_out;
  char* ws = (char*)d_ws;

  float* out_loss = out;                     // [0]
  float* out_perp = out + 1 + NROWS * DIM;   // [33554433]
  float* encf     = out + 2 + NROWS * DIM;   // [33554434 ..), 16B-aligned

  short8* WhT8   = (short8*)ws;                        // 1 MB
  float*  wnorm  = (float*)(ws + (1040u << 10));       // 4 KB
  int*    counts = (int*)(ws + (1040u << 10) + 4096);  // 4 KB
  double* sums   = (double*)(ws + (1040u << 10) + 8192); // [0]=sumX2 [1]=sumS

  wprep_kernel<<<KC / 4, 256, 0, stream>>>(W, WhT8, wnorm, counts, sums);
  mm_kernel<<<NROWS / 256, 256, 0, stream>>>(X, W, (const u16*)WhT8, wnorm,
                                             counts, sums, out, encf);
  finalize_kernel<<<1, 256, 0, stream>>>(counts, sums, out_loss, out_perp);
}

// Round 13
// 245.345 us; speedup vs baseline: 1.0118x; 1.0118x over previous
//
#include <hip/hip_runtime.h>
#include <stdint.h>

typedef unsigned short u16;
typedef unsigned long long u64;
using short8 = __attribute__((ext_vector_type(8))) short;
using f32x16 = __attribute__((ext_vector_type(16))) float;
using f32x4v = __attribute__((ext_vector_type(4))) float;

#define NROWS 65536
#define DIM   512
#define KC    1024

#define GLOBAL_AS __attribute__((address_space(1)))
#define LDS_AS    __attribute__((address_space(3)))

__device__ __forceinline__ void gload_lds16(const void* g, void* l) {
  __builtin_amdgcn_global_load_lds((const GLOBAL_AS uint32_t*)g,
                                   (LDS_AS uint32_t*)l, 16, 0, 0);
}

__device__ __forceinline__ u16 f2bf(float f) {  // RNE float->bf16 bits
  unsigned u = __float_as_uint(f);
  return (u16)((u + 0x7fffu + ((u >> 16) & 1u)) >> 16);
}

__device__ __forceinline__ f32x4v ntload4(const float* p) {
  return __builtin_nontemporal_load((const f32x4v*)p);
}
__device__ __forceinline__ void ntstore4(float* p, f32x4v v) {
  __builtin_nontemporal_store(v, (f32x4v*)p);
}

// ---- W prep: W^T in MFMA-B-fragment order (32-code tiles) + ||w||^2 -------
__global__ __launch_bounds__(256) void wprep_kernel(const float* __restrict__ W,
                                                    short8* __restrict__ WhT8,
                                                    float* __restrict__ wnorm,
                                                    int* __restrict__ counts,
                                                    double* __restrict__ sums) {
  if (blockIdx.x == 0) {
    for (int k = threadIdx.x; k < KC; k += 256) counts[k] = 0;
    if (threadIdx.x < 2) sums[threadIdx.x] = 0.0;
  }
  int code = blockIdx.x * 4 + (threadIdx.x >> 6);
  int l = threadIdx.x & 63;
  const float* wr = W + (size_t)code * DIM + l * 8;
  float4 v0 = *(const float4*)wr;
  float4 v1 = *(const float4*)(wr + 4);
  float s = v0.x * v0.x + v0.y * v0.y + v0.z * v0.z + v0.w * v0.w
          + v1.x * v1.x + v1.y * v1.y + v1.z * v1.z + v1.w * v1.w;
  short8 pk;
  pk[0] = (short)f2bf(v0.x); pk[1] = (short)f2bf(v0.y);
  pk[2] = (short)f2bf(v0.z); pk[3] = (short)f2bf(v0.w);
  pk[4] = (short)f2bf(v1.x); pk[5] = (short)f2bf(v1.y);
  pk[6] = (short)f2bf(v1.z); pk[7] = (short)f2bf(v1.w);
  WhT8[(size_t)(code >> 5) * 2048 + (l >> 1) * 64 + (l & 1) * 32 + (code & 31)] = pk;
#pragma unroll
  for (int off = 32; off; off >>= 1) s += __shfl_xor(s, off, 64);
  if (l == 0) wnorm[code] = s;
}

// ---- main fused kernel: wave-role split -----------------------------------
// 512 thr = 8 waves, 1 block/CU (VGPR-capped), block = 128 rows.
// Waves 0-3: GEMM+argmin (A in regs, B dbuf LDS).  Waves 4-7: stream the
// block's enc-zero stripe (512 KB) concurrently.  Shared tail: quant+one-hot.
__global__ __launch_bounds__(512)
__attribute__((amdgpu_waves_per_eu(2, 2))) void mm_kernel(
    const float* __restrict__ X, const float* __restrict__ W,
    const u16* __restrict__ WhTf, const float* __restrict__ wnorm,
    int* __restrict__ counts, double* __restrict__ sums,
    float* __restrict__ out, float* __restrict__ encf) {
  __shared__ __align__(16) u16 BsU[2][16384];  // 2 x 32 KB
  __shared__ int rowk[128];
  __shared__ double sdbl[4];
  const int t = threadIdx.x;
  const int w = t >> 6, l = t & 63;
  const int r = l & 31, h = l >> 5;
  const int row0 = blockIdx.x * 128;
  const bool mmw = (w < 4);

  short8 aF[32];
  unsigned best_[16];
  f32x4v* encz = (f32x4v*)(encf + (size_t)row0 * KC);
  const f32x4v zero4 = {0.f, 0.f, 0.f, 0.f};

  if (mmw) {
    // tile 0 DMA: 8 gloads/wave cover 32 KB
#pragma unroll
    for (int i = 0; i < 8; ++i)
      gload_lds16(WhTf + ((w * 8 + i) * 512 + l * 8),
                  &BsU[0][(w * 8 + i) * 512 + l * 8]);
    // A panel (32 rows x 512) -> regs as MFMA A-frags; fused sum(x^2)
    const float* Xr = X + (size_t)(row0 + w * 32 + r) * DIM + h * 8;
    double xacc = 0.0;
#pragma unroll
    for (int s = 0; s < 32; ++s) {
      f32x4v v0 = ntload4(Xr + s * 16);
      f32x4v v1 = ntload4(Xr + s * 16 + 4);
      xacc += (double)v0[0] * v0[0] + (double)v0[1] * v0[1] + (double)v0[2] * v0[2] + (double)v0[3] * v0[3]
            + (double)v1[0] * v1[0] + (double)v1[1] * v1[1] + (double)v1[2] * v1[2] + (double)v1[3] * v1[3];
      short8 pk;
      pk[0] = (short)f2bf(v0[0]); pk[1] = (short)f2bf(v0[1]);
      pk[2] = (short)f2bf(v0[2]); pk[3] = (short)f2bf(v0[3]);
      pk[4] = (short)f2bf(v1[0]); pk[5] = (short)f2bf(v1[1]);
      pk[6] = (short)f2bf(v1[2]); pk[7] = (short)f2bf(v1[3]);
      aF[s] = pk;
    }
#pragma unroll
    for (int off = 32; off; off >>= 1) xacc += __shfl_xor(xacc, off, 64);
    if (l == 0) atomicAdd(&sums[0], xacc);
#pragma unroll
    for (int q = 0; q < 16; ++q) best_[q] = 0xFFFFFFFFu;
    asm volatile("s_waitcnt vmcnt(0)" ::: "memory");  // tile 0 resident
  }
  __builtin_amdgcn_s_barrier();
  __builtin_amdgcn_sched_barrier(0);

  for (int kt = 0; kt < 32; ++kt) {
    if (mmw) {
      const int buf = kt & 1;
      if (kt < 31) {  // issue-early next-tile DMA
        const u16* src = WhTf + (size_t)(kt + 1) * 16384;
#pragma unroll
        for (int i = 0; i < 8; ++i)
          gload_lds16(src + ((w * 8 + i) * 512 + l * 8),
                      &BsU[buf ^ 1][(w * 8 + i) * 512 + l * 8]);
      }
      const u16* bufp = &BsU[buf][l * 8];
      f32x16 acc_e = {}, acc_o = {};
#pragma unroll
      for (int ks = 0; ks < 32; ++ks) {
        short8 bv = *(const short8*)&bufp[ks * 512];
        if (ks & 1)
          acc_o = __builtin_amdgcn_mfma_f32_32x32x16_bf16(aF[ks], bv, acc_o, 0, 0, 0);
        else
          acc_e = __builtin_amdgcn_mfma_f32_32x32x16_bf16(aF[ks], bv, acc_e, 0, 0, 0);
      }
      float wn = wnorm[kt * 32 + r];
      unsigned col = (unsigned)(kt * 32 + r);
#pragma unroll
      for (int q = 0; q < 16; ++q) {
        float sc = fmaf(-2.0f, acc_e[q] + acc_o[q], wn);
        unsigned u_ = __float_as_uint(sc);
        unsigned key = (u_ & 0x80000000u) ? ~u_ : (u_ | 0x80000000u);
        best_[q] = min(best_[q], (key & 0xFFFFFC00u) | col);
      }
      asm volatile("s_waitcnt vmcnt(0)" ::: "memory");  // next tile landed
    } else {
      // streamer waves: 16 KB of enc-zeros per iter (this block's stripe)
      const int ew = w - 4;
#pragma unroll
      for (int j = 0; j < 4; ++j)
        __builtin_nontemporal_store(zero4,
                                    &encz[kt * 1024 + ew * 256 + j * 64 + l]);
    }
    __builtin_amdgcn_s_barrier();
    __builtin_amdgcn_sched_barrier(0);
  }

  if (mmw) {
    // per-row argmin across the 32 code-lanes; rowk + stats
    double local = 0.0;
#pragma unroll
    for (int q = 0; q < 16; ++q) {
      unsigned pb = best_[q];
#pragma unroll
      for (int off = 16; off; off >>= 1)
        pb = min(pb, (unsigned)__shfl_xor((int)pb, off, 32));
      if (r == 0) {
        int rit = w * 32 + (q & 3) + 8 * (q >> 2) + 4 * h;
        int k = (int)(pb & 1023u);
        rowk[rit] = k;
        atomicAdd(&counts[k], 1);
        unsigned key = (pb & 0xFFFFFC00u) | 0x200u;  // midpoint reconstruction
        unsigned uu = (key & 0x80000000u) ? (key ^ 0x80000000u) : ~key;
        local += (double)__uint_as_float(uu);
      }
    }
    double o32 = __shfl(local, 32, 64);
    if (l == 0) sdbl[w] = local + o32;
  } else {
    asm volatile("s_waitcnt vmcnt(0)" ::: "memory");  // zeros committed
  }
  __syncthreads();
  if (t == 0) atomicAdd(&sums[1], sdbl[0] + sdbl[1] + sdbl[2] + sdbl[3]);

  // shared tail (8 waves x 16 rows): quant gather-write + one-hot 1.0
  for (int j = 0; j < 16; ++j) {
    int rit = w * 16 + j;
    int k = rowk[rit];
    const float* Wr = W + (size_t)k * DIM;
    size_t ob = (size_t)(row0 + rit) * DIM;
    {
      f32x4v cm = *(const f32x4v*)(Wr + 4 * l);
      f32x4v c1 = *(const f32x4v*)(Wr + 4 * l + 4);
      f32x4v sv = {cm[3], c1[0], c1[1], c1[2]};
      ntstore4(out + ob + 4 + 4 * l, sv);
    }
    if (l <= 62) {
      int m = l + 64;
      f32x4v dm = *(const f32x4v*)(Wr + 4 * m);
      f32x4v d1 = *(const f32x4v*)(Wr + 4 * m + 4);
      f32x4v sv = {dm[3], d1[0], d1[1], d1[2]};
      ntstore4(out + ob + 4 + 4 * m, sv);
    }
    if (l < 3) out[ob + 1 + l] = Wr[l];        // head d=0,1,2
    if (l == 3) out[ob + 512] = Wr[511];       // tail d=511
    if (l == 4) encf[(size_t)(row0 + rit) * KC + k] = 1.0f;  // one-hot
  }
}

// ---- finalize: loss + perplexity ------------------------------------------
__global__ __launch_bounds__(256) void finalize_kernel(
    const int* __restrict__ counts, const double* __restrict__ sums,
    float* __restrict__ out_loss, float* __restrict__ out_perp) {
  __shared__ float red[4];
  int t = threadIdx.x;
  float h = 0.f;
  for (int k = t; k < KC; k += 256) {
    float p = (float)counts[k] / (float)NROWS;
    h -= p * logf(p + 1e-10f);
  }
#pragma unroll
  for (int off = 32; off; off >>= 1) h += __shfl_xor(h, off, 64);
  if ((t & 63) == 0) red[t >> 6] = h;
  __syncthreads();
  if (t == 0) {
    float H = red[0] + red[1] + red[2] + red[3];
    *out_perp = expf(H);
    double m = (sums[0] + sums[1]) / (double)((long long)NROWS * DIM);
    *out_loss = (float)(1.25 * m);
  }
}

extern "C" void kernel_launch(void* const* d_in, const int* in_sizes, int n_in,
                              void* d_out, int out_size, void* d_ws, size_t ws_size,
                              hipStream_t stream) {
  const float* X = (const float*)d_in[0];
  const float* W = (const float*)d_in[1];
  float* out = (float*)d_out;
  char* ws = (char*)d_ws;

  float* out_loss = out;                     // [0]
  float* out_perp = out + 1 + NROWS * DIM;   // [33554433]
  float* encf     = out + 2 + NROWS * DIM;   // [33554434 ..), 16B-aligned

  short8* WhT8   = (short8*)ws;                        // 1 MB
  float*  wnorm  = (float*)(ws + (1040u << 10));       // 4 KB
  int*    counts = (int*)(ws + (1040u << 10) + 4096);  // 4 KB
  double* sums   = (double*)(ws + (1040u << 10) + 8192); // [0]=sumX2 [1]=sumS

  wprep_kernel<<<KC / 4, 256, 0, stream>>>(W, WhT8, wnorm, counts, sums);
  mm_kernel<<<NROWS / 128, 512, 0, stream>>>(X, W, (const u16*)WhT8, wnorm,
                                             counts, sums, out, encf);
  finalize_kernel<<<1, 256, 0, stream>>>(counts, sums, out_loss, out_perp);
}

// Round 14
// 234.138 us; speedup vs baseline: 1.0602x; 1.0479x over previous
//
#include <hip/hip_runtime.h>
#include <stdint.h>

typedef unsigned short u16;
typedef unsigned long long u64;
using short8 = __attribute__((ext_vector_type(8))) short;
using f32x16 = __attribute__((ext_vector_type(16))) float;
using f32x4v = __attribute__((ext_vector_type(4))) float;

#define NROWS 65536
#define DIM   512
#define KC    1024

#define GLOBAL_AS __attribute__((address_space(1)))
#define LDS_AS    __attribute__((address_space(3)))

__device__ __forceinline__ void gload_lds16(const void* g, void* l) {
  __builtin_amdgcn_global_load_lds((const GLOBAL_AS uint32_t*)g,
                                   (LDS_AS uint32_t*)l, 16, 0, 0);
}

__device__ __forceinline__ u16 f2bf(float f) {  // RNE float->bf16 bits
  unsigned u = __float_as_uint(f);
  return (u16)((u + 0x7fffu + ((u >> 16) & 1u)) >> 16);
}

__device__ __forceinline__ f32x4v ntload4(const float* p) {
  return __builtin_nontemporal_load((const f32x4v*)p);
}
__device__ __forceinline__ void ntstore4(float* p, f32x4v v) {
  __builtin_nontemporal_store(v, (f32x4v*)p);
}

// ---- W prep: W^T in MFMA-B-fragment order (32-code groups) + ||w||^2 ------
__global__ __launch_bounds__(256) void wprep_kernel(const float* __restrict__ W,
                                                    short8* __restrict__ WhT8,
                                                    float* __restrict__ wnorm,
                                                    int* __restrict__ counts,
                                                    double* __restrict__ sums) {
  if (blockIdx.x == 0) {
    for (int k = threadIdx.x; k < KC; k += 256) counts[k] = 0;
    if (threadIdx.x < 2) sums[threadIdx.x] = 0.0;
  }
  int code = blockIdx.x * 4 + (threadIdx.x >> 6);
  int l = threadIdx.x & 63;
  const float* wr = W + (size_t)code * DIM + l * 8;
  float4 v0 = *(const float4*)wr;
  float4 v1 = *(const float4*)(wr + 4);
  float s = v0.x * v0.x + v0.y * v0.y + v0.z * v0.z + v0.w * v0.w
          + v1.x * v1.x + v1.y * v1.y + v1.z * v1.z + v1.w * v1.w;
  short8 pk;
  pk[0] = (short)f2bf(v0.x); pk[1] = (short)f2bf(v0.y);
  pk[2] = (short)f2bf(v0.z); pk[3] = (short)f2bf(v0.w);
  pk[4] = (short)f2bf(v1.x); pk[5] = (short)f2bf(v1.y);
  pk[6] = (short)f2bf(v1.z); pk[7] = (short)f2bf(v1.w);
  WhT8[(size_t)(code >> 5) * 2048 + (l >> 1) * 64 + (l & 1) * 32 + (code & 31)] = pk;
#pragma unroll
  for (int off = 32; off; off >>= 1) s += __shfl_xor(s, off, 64);
  if (l == 0) wnorm[code] = s;
}

// ---- main fused kernel (R10 base, 64-code tiles, store-slack vmcnt) -------
// 256 thr = 4 waves x 32 rows; grid 512 = 2 blocks/CU. A in regs; B streams
// 64-code tiles (2 x 32 KB dbuf LDS); per tile: 16 gloads (oldest) + 8 NT
// enc-stores (newest) -> vmcnt(8) drain leaves stores a full tile of slack.
__global__ __launch_bounds__(256)
__attribute__((amdgpu_waves_per_eu(2, 2))) void mm_kernel(
    const float* __restrict__ X, const float* __restrict__ W,
    const u16* __restrict__ WhTf, const float* __restrict__ wnorm,
    int* __restrict__ counts, double* __restrict__ sums,
    float* __restrict__ out, float* __restrict__ encf) {
  __shared__ __align__(16) u16 BsU[2][32768];  // 2 x 64 KB? no: 2 x 32768 u16 = 2 x 64 KB... (64-code tile = 64 KB)
  __shared__ int rowk[128];
  __shared__ double sdbl[4];
  const int t = threadIdx.x;
  const int w = t >> 6, l = t & 63;
  const int r = l & 31, h = l >> 5;
  const int row0 = blockIdx.x * 128;

  // kick off tile 0 DMA (16 gloads/wave x 4 waves = 64 KB)
#pragma unroll
  for (int i = 0; i < 16; ++i)
    gload_lds16(WhTf + ((w * 16 + i) * 512 + l * 8),
                &BsU[0][(w * 16 + i) * 512 + l * 8]);

  // A panel (32 rows x 512) -> regs as MFMA A-frags (NT loads), sum(x^2)
  const float* Xr = X + (size_t)(row0 + w * 32 + r) * DIM + h * 8;
  short8 aF[32];
  double xacc = 0.0;
#pragma unroll
  for (int s = 0; s < 32; ++s) {
    f32x4v v0 = ntload4(Xr + s * 16);
    f32x4v v1 = ntload4(Xr + s * 16 + 4);
    xacc += (double)v0[0] * v0[0] + (double)v0[1] * v0[1] + (double)v0[2] * v0[2] + (double)v0[3] * v0[3]
          + (double)v1[0] * v1[0] + (double)v1[1] * v1[1] + (double)v1[2] * v1[2] + (double)v1[3] * v1[3];
    short8 pk;
    pk[0] = (short)f2bf(v0[0]); pk[1] = (short)f2bf(v0[1]);
    pk[2] = (short)f2bf(v0[2]); pk[3] = (short)f2bf(v0[3]);
    pk[4] = (short)f2bf(v1[0]); pk[5] = (short)f2bf(v1[1]);
    pk[6] = (short)f2bf(v1[2]); pk[7] = (short)f2bf(v1[3]);
    aF[s] = pk;
  }
#pragma unroll
  for (int off = 32; off; off >>= 1) xacc += __shfl_xor(xacc, off, 64);
  if (l == 0) atomicAdd(&sums[0], xacc);

  unsigned best_[16];
#pragma unroll
  for (int q = 0; q < 16; ++q) best_[q] = 0xFFFFFFFFu;

  f32x4v* encz = (f32x4v*)(encf + (size_t)row0 * KC);
  const f32x4v zero4 = {0.f, 0.f, 0.f, 0.f};

  asm volatile("s_waitcnt vmcnt(0)" ::: "memory");  // tile 0 resident
  __builtin_amdgcn_s_barrier();
  __builtin_amdgcn_sched_barrier(0);

  for (int kt = 0; kt < 16; ++kt) {
    const int buf = kt & 1;
    if (kt < 15) {  // prefetch next 64-code tile FIRST (16 gloads = oldest)
      const u16* src = WhTf + (size_t)(kt + 1) * 32768;
#pragma unroll
      for (int i = 0; i < 16; ++i)
        gload_lds16(src + ((w * 16 + i) * 512 + l * 8),
                    &BsU[buf ^ 1][(w * 16 + i) * 512 + l * 8]);
    }
    // enc-zero NT stream AFTER gloads (8 stores = newest; get full-tile slack)
#pragma unroll
    for (int j = 0; j < 8; ++j)
      __builtin_nontemporal_store(zero4, &encz[kt * 2048 + j * 256 + t]);

    const u16* bufp = &BsU[buf][l * 8];
#pragma unroll
    for (int cb = 0; cb < 2; ++cb) {
      f32x16 acc_e = {}, acc_o = {};
#pragma unroll
      for (int ks = 0; ks < 32; ++ks) {
        short8 bv = *(const short8*)&bufp[cb * 16384 + ks * 512];
        if (ks & 1)
          acc_o = __builtin_amdgcn_mfma_f32_32x32x16_bf16(aF[ks], bv, acc_o, 0, 0, 0);
        else
          acc_e = __builtin_amdgcn_mfma_f32_32x32x16_bf16(aF[ks], bv, acc_e, 0, 0, 0);
      }
      float wn = wnorm[kt * 64 + cb * 32 + r];
      unsigned col = (unsigned)(kt * 64 + cb * 32 + r);
#pragma unroll
      for (int q = 0; q < 16; ++q) {
        float sc = fmaf(-2.0f, acc_e[q] + acc_o[q], wn);
        unsigned u_ = __float_as_uint(sc);
        unsigned key = (u_ & 0x80000000u) ? ~u_ : (u_ | 0x80000000u);
        best_[q] = min(best_[q], (key & 0xFFFFFC00u) | col);
      }
    }
    // drain prev stores + this tile's gloads; leave our 8 stores in flight
    asm volatile("s_waitcnt vmcnt(8)" ::: "memory");
    __builtin_amdgcn_s_barrier();
    __builtin_amdgcn_sched_barrier(0);
  }

  // per-row argmin across the 32 code-lanes; rowk + stats
  double local = 0.0;
#pragma unroll
  for (int q = 0; q < 16; ++q) {
    unsigned pb = best_[q];
#pragma unroll
    for (int off = 16; off; off >>= 1)
      pb = min(pb, (unsigned)__shfl_xor((int)pb, off, 32));
    if (r == 0) {
      int rit = w * 32 + (q & 3) + 8 * (q >> 2) + 4 * h;
      int k = (int)(pb & 1023u);
      rowk[rit] = k;
      atomicAdd(&counts[k], 1);
      unsigned key = (pb & 0xFFFFFC00u) | 0x200u;  // midpoint reconstruction
      unsigned uu = (key & 0x80000000u) ? (key ^ 0x80000000u) : ~key;
      local += (double)__uint_as_float(uu);
    }
  }
  {
    double o32 = __shfl(local, 32, 64);
    if (l == 0) sdbl[w] = local + o32;
  }
  __syncthreads();  // full drain: zeros committed before 1.0 scatter
  if (t == 0) atomicAdd(&sums[1], sdbl[0] + sdbl[1] + sdbl[2] + sdbl[3]);

  // fused quantized gather-write (aligned f4 NT around +1 base) + one-hot
  for (int j = 0; j < 32; ++j) {
    int rit = w * 32 + j;
    int k = rowk[rit];
    const float* Wr = W + (size_t)k * DIM;
    size_t ob = (size_t)(row0 + rit) * DIM;
    {
      f32x4v cm = *(const f32x4v*)(Wr + 4 * l);
      f32x4v c1 = *(const f32x4v*)(Wr + 4 * l + 4);
      f32x4v sv = {cm[3], c1[0], c1[1], c1[2]};
      ntstore4(out + ob + 4 + 4 * l, sv);
    }
    if (l <= 62) {
      int m = l + 64;
      f32x4v dm = *(const f32x4v*)(Wr + 4 * m);
      f32x4v d1 = *(const f32x4v*)(Wr + 4 * m + 4);
      f32x4v sv = {dm[3], d1[0], d1[1], d1[2]};
      ntstore4(out + ob + 4 + 4 * m, sv);
    }
    if (l < 3) out[ob + 1 + l] = Wr[l];        // head d=0,1,2
    if (l == 3) out[ob + 512] = Wr[511];       // tail d=511
    if (l == 4) encf[(size_t)(row0 + rit) * KC + k] = 1.0f;  // one-hot
  }
}

// ---- finalize: loss + perplexity ------------------------------------------
__global__ __launch_bounds__(256) void finalize_kernel(
    const int* __restrict__ counts, const double* __restrict__ sums,
    float* __restrict__ out_loss, float* __restrict__ out_perp) {
  __shared__ float red[4];
  int t = threadIdx.x;
  float h = 0.f;
  for (int k = t; k < KC; k += 256) {
    float p = (float)counts[k] / (float)NROWS;
    h -= p * logf(p + 1e-10f);
  }
#pragma unroll
  for (int off = 32; off; off >>= 1) h += __shfl_xor(h, off, 64);
  if ((t & 63) == 0) red[t >> 6] = h;
  __syncthreads();
  if (t == 0) {
    float H = red[0] + red[1] + red[2] + red[3];
    *out_perp = expf(H);
    double m = (sums[0] + sums[1]) / (double)((long long)NROWS * DIM);
    *out_loss = (float)(1.25 * m);
  }
}

extern "C" void kernel_launch(void* const* d_in, const int* in_sizes, int n_in,
                              void* d_out, int out_size, void* d_ws, size_t ws_size,
                              hipStream_t stream) {
  const float* X = (const float*)d_in[0];
  const float* W = (const float*)d_in[1];
  float* out = (float*)d_out;
  char* ws = (char*)d_ws;

  float* out_loss = out;                     // [0]
  float* out_perp = out + 1 + NROWS * DIM;   // [33554433]
  float* encf     = out + 2 + NROWS * DIM;   // [33554434 ..), 16B-aligned

  short8* WhT8   = (short8*)ws;                        // 1 MB
  float*  wnorm  = (float*)(ws + (1040u << 10));       // 4 KB
  int*    counts = (int*)(ws + (1040u << 10) + 4096);  // 4 KB
  double* sums   = (double*)(ws + (1040u << 10) + 8192); // [0]=sumX2 [1]=sumS

  wprep_kernel<<<KC / 4, 256, 0, stream>>>(W, WhT8, wnorm, counts, sums);
  mm_kernel<<<NROWS / 128, 256, 0, stream>>>(X, W, (const u16*)WhT8, wnorm,
                                             counts, sums, out, encf);
  finalize_kernel<<<1, 256, 0, stream>>>(counts, sums, out_loss, out_perp);
}

// Round 15
// 188.029 us; speedup vs baseline: 1.3202x; 1.2452x over previous
//
#include <hip/hip_runtime.h>
#include <stdint.h>

typedef unsigned short u16;
typedef unsigned long long u64;
using short8 = __attribute__((ext_vector_type(8))) short;
using f32x16 = __attribute__((ext_vector_type(16))) float;
using f32x4v = __attribute__((ext_vector_type(4))) float;

#define NROWS 65536
#define DIM   512
#define KC    1024

#define GLOBAL_AS __attribute__((address_space(1)))
#define LDS_AS    __attribute__((address_space(3)))

__device__ __forceinline__ void gload_lds16(const void* g, void* l) {
  __builtin_amdgcn_global_load_lds((const GLOBAL_AS uint32_t*)g,
                                   (LDS_AS uint32_t*)l, 16, 0, 0);
}

__device__ __forceinline__ u16 f2bf(float f) {  // RNE float->bf16 bits
  unsigned u = __float_as_uint(f);
  return (u16)((u + 0x7fffu + ((u >> 16) & 1u)) >> 16);
}

__device__ __forceinline__ f32x4v ntload4(const float* p) {
  return __builtin_nontemporal_load((const f32x4v*)p);
}
__device__ __forceinline__ void ntstore4(float* p, f32x4v v) {
  __builtin_nontemporal_store(v, (f32x4v*)p);
}

// ---- W prep: W^T in fragment order [cg(32 codes)][khalf(K=256)][ks(16)] ----
// Each frag = 1 KB: lane (h*32+r) holds W[cg*32+r][khalf*256+ks*16+8h .. +8).
__global__ __launch_bounds__(256) void wprep_kernel(const float* __restrict__ W,
                                                    short8* __restrict__ WhT8,
                                                    float* __restrict__ wnorm,
                                                    int* __restrict__ counts,
                                                    double* __restrict__ sums) {
  if (blockIdx.x == 0) {
    for (int k = threadIdx.x; k < KC; k += 256) counts[k] = 0;
    if (threadIdx.x < 2) sums[threadIdx.x] = 0.0;
  }
  int code = blockIdx.x * 4 + (threadIdx.x >> 6);
  int l = threadIdx.x & 63;
  const float* wr = W + (size_t)code * DIM + l * 8;
  float4 v0 = *(const float4*)wr;
  float4 v1 = *(const float4*)(wr + 4);
  float s = v0.x * v0.x + v0.y * v0.y + v0.z * v0.z + v0.w * v0.w
          + v1.x * v1.x + v1.y * v1.y + v1.z * v1.z + v1.w * v1.w;
  short8 pk;
  pk[0] = (short)f2bf(v0.x); pk[1] = (short)f2bf(v0.y);
  pk[2] = (short)f2bf(v0.z); pk[3] = (short)f2bf(v0.w);
  pk[4] = (short)f2bf(v1.x); pk[5] = (short)f2bf(v1.y);
  pk[6] = (short)f2bf(v1.z); pk[7] = (short)f2bf(v1.w);
  // lane l covers K [8l, 8l+8): global frag p = l>>1, khalf = l>>5, ks = (l>>1)&15
  WhT8[(size_t)(code >> 5) * 2048 + (size_t)(l >> 5) * 1024 +
       (size_t)((l >> 1) & 15) * 64 + (l & 1) * 32 + (code & 31)] = pk;
#pragma unroll
  for (int off = 32; off; off >>= 1) s += __shfl_xor(s, off, 64);
  if (l == 0) wnorm[code] = s;
}

// ---- main fused kernel: 4-buffer ring, 2-tile-deep prefetch ---------------
// 256 thr = 4 waves x 32 rows; grid 512 = 2 blocks/CU (LDS 66 KB!). A in regs.
// 64 tiles of (32 codes x K=256) = 16 KB each; DMA issued 2 tiles ahead, so
// every vmcnt(6) drain targets loads issued 2 phases ago (zero latency cost);
// enc-stores ride in the newest-6 window with >=1 phase of slack.
__global__ __launch_bounds__(256)
__attribute__((amdgpu_waves_per_eu(2, 2))) void mm_kernel(
    const float* __restrict__ X, const float* __restrict__ W,
    const u16* __restrict__ WhTf, const float* __restrict__ wnorm,
    int* __restrict__ counts, double* __restrict__ sums,
    float* __restrict__ out, float* __restrict__ encf) {
  __shared__ __align__(16) u16 BsU[4][8192];  // 4 x 16 KB ring
  __shared__ int rowk[128];
  __shared__ double sdbl[4];
  const int t = threadIdx.x;
  const int w = t >> 6, l = t & 63;
  const int r = l & 31, h = l >> 5;
  const int row0 = blockIdx.x * 128;

  // prologue: DMA tiles 0,1,2 into bufs 0,1,2
#pragma unroll
  for (int pt = 0; pt < 3; ++pt)
#pragma unroll
    for (int i = 0; i < 4; ++i)
      gload_lds16(WhTf + (size_t)pt * 8192 + (i * 256 + t) * 8,
                  &BsU[pt][(i * 256 + t) * 8]);

  // A panel (32 rows x 512) -> regs as MFMA A-frags (NT loads), sum(x^2)
  const float* Xr = X + (size_t)(row0 + w * 32 + r) * DIM + h * 8;
  short8 aF[32];
  double xacc = 0.0;
#pragma unroll
  for (int s = 0; s < 32; ++s) {
    f32x4v v0 = ntload4(Xr + s * 16);
    f32x4v v1 = ntload4(Xr + s * 16 + 4);
    xacc += (double)v0[0] * v0[0] + (double)v0[1] * v0[1] + (double)v0[2] * v0[2] + (double)v0[3] * v0[3]
          + (double)v1[0] * v1[0] + (double)v1[1] * v1[1] + (double)v1[2] * v1[2] + (double)v1[3] * v1[3];
    short8 pk;
    pk[0] = (short)f2bf(v0[0]); pk[1] = (short)f2bf(v0[1]);
    pk[2] = (short)f2bf(v0[2]); pk[3] = (short)f2bf(v0[3]);
    pk[4] = (short)f2bf(v1[0]); pk[5] = (short)f2bf(v1[1]);
    pk[6] = (short)f2bf(v1[2]); pk[7] = (short)f2bf(v1[3]);
    aF[s] = pk;
  }
#pragma unroll
  for (int off = 32; off; off >>= 1) xacc += __shfl_xor(xacc, off, 64);
  if (l == 0) atomicAdd(&sums[0], xacc);

  unsigned best_[16];
#pragma unroll
  for (int q = 0; q < 16; ++q) best_[q] = 0xFFFFFFFFu;

  f32x4v* encz = (f32x4v*)(encf + (size_t)row0 * KC);
  const f32x4v zero4 = {0.f, 0.f, 0.f, 0.f};

  asm volatile("s_waitcnt vmcnt(0)" ::: "memory");  // tiles 0..2 resident
  __builtin_amdgcn_s_barrier();
  __builtin_amdgcn_sched_barrier(0);

  for (int cg = 0; cg < 32; ++cg) {
    f32x16 acc_e = {}, acc_o = {};
#pragma unroll
    for (int khalf = 0; khalf < 2; ++khalf) {
      const int kt = cg * 2 + khalf;
      // DMA tile kt+2 (clamped; redundant re-reads of tile 63 are harmless)
      {
        const int nt = (kt + 2 < 64) ? kt + 2 : 63;
        const u16* src = WhTf + (size_t)nt * 8192;
#pragma unroll
        for (int i = 0; i < 4; ++i)
          gload_lds16(src + (i * 256 + t) * 8,
                      &BsU[(kt + 2) & 3][(i * 256 + t) * 8]);
      }
      // enc-zero NT stream (2 stores; stay in the newest-6 window)
#pragma unroll
      for (int j = 0; j < 2; ++j)
        __builtin_nontemporal_store(zero4, &encz[kt * 512 + j * 256 + t]);

      const u16* bufp = &BsU[kt & 3][l * 8];
#pragma unroll
      for (int ks = 0; ks < 16; ++ks) {
        short8 bv = *(const short8*)&bufp[ks * 512];
        if (ks & 1)
          acc_o = __builtin_amdgcn_mfma_f32_32x32x16_bf16(aF[khalf * 16 + ks], bv, acc_o, 0, 0, 0);
        else
          acc_e = __builtin_amdgcn_mfma_f32_32x32x16_bf16(aF[khalf * 16 + ks], bv, acc_e, 0, 0, 0);
      }
      if (khalf) {
        float wn = wnorm[cg * 32 + r];
        unsigned col = (unsigned)(cg * 32 + r);
#pragma unroll
        for (int q = 0; q < 16; ++q) {
          float sc = fmaf(-2.0f, acc_e[q] + acc_o[q], wn);
          unsigned u_ = __float_as_uint(sc);
          unsigned key = (u_ & 0x80000000u) ? ~u_ : (u_ | 0x80000000u);
          best_[q] = min(best_[q], (key & 0xFFFFFC00u) | col);
        }
      }
      // keep newest 6 (gloads kt+2 + stores kt); drains gloads kt+1 (2-old)
      asm volatile("s_waitcnt vmcnt(6)" ::: "memory");
      __builtin_amdgcn_s_barrier();
      __builtin_amdgcn_sched_barrier(0);
    }
  }

  // per-row argmin across the 32 code-lanes; rowk + stats
  double local = 0.0;
#pragma unroll
  for (int q = 0; q < 16; ++q) {
    unsigned pb = best_[q];
#pragma unroll
    for (int off = 16; off; off >>= 1)
      pb = min(pb, (unsigned)__shfl_xor((int)pb, off, 32));
    if (r == 0) {
      int rit = w * 32 + (q & 3) + 8 * (q >> 2) + 4 * h;
      int k = (int)(pb & 1023u);
      rowk[rit] = k;
      atomicAdd(&counts[k], 1);
      unsigned key = (pb & 0xFFFFFC00u) | 0x200u;  // midpoint reconstruction
      unsigned uu = (key & 0x80000000u) ? (key ^ 0x80000000u) : ~key;
      local += (double)__uint_as_float(uu);
    }
  }
  {
    double o32 = __shfl(local, 32, 64);
    if (l == 0) sdbl[w] = local + o32;
  }
  __syncthreads();  // full drain: zeros committed before 1.0 scatter
  if (t == 0) atomicAdd(&sums[1], sdbl[0] + sdbl[1] + sdbl[2] + sdbl[3]);

  // fused quantized gather-write (aligned f4 NT around +1 base) + one-hot
  for (int j = 0; j < 32; ++j) {
    int rit = w * 32 + j;
    int k = rowk[rit];
    const float* Wr = W + (size_t)k * DIM;
    size_t ob = (size_t)(row0 + rit) * DIM;
    {
      f32x4v cm = *(const f32x4v*)(Wr + 4 * l);
      f32x4v c1 = *(const f32x4v*)(Wr + 4 * l + 4);
      f32x4v sv = {cm[3], c1[0], c1[1], c1[2]};
      ntstore4(out + ob + 4 + 4 * l, sv);
    }
    if (l <= 62) {
      int m = l + 64;
      f32x4v dm = *(const f32x4v*)(Wr + 4 * m);
      f32x4v d1 = *(const f32x4v*)(Wr + 4 * m + 4);
      f32x4v sv = {dm[3], d1[0], d1[1], d1[2]};
      ntstore4(out + ob + 4 + 4 * m, sv);
    }
    if (l < 3) out[ob + 1 + l] = Wr[l];        // head d=0,1,2
    if (l == 3) out[ob + 512] = Wr[511];       // tail d=511
    if (l == 4) encf[(size_t)(row0 + rit) * KC + k] = 1.0f;  // one-hot
  }
}

// ---- finalize: loss + perplexity ------------------------------------------
__global__ __launch_bounds__(256) void finalize_kernel(
    const int* __restrict__ counts, const double* __restrict__ sums,
    float* __restrict__ out_loss, float* __restrict__ out_perp) {
  __shared__ float red[4];
  int t = threadIdx.x;
  float h = 0.f;
  for (int k = t; k < KC; k += 256) {
    float p = (float)counts[k] / (float)NROWS;
    h -= p * logf(p + 1e-10f);
  }
#pragma unroll
  for (int off = 32; off; off >>= 1) h += __shfl_xor(h, off, 64);
  if ((t & 63) == 0) red[t >> 6] = h;
  __syncthreads();
  if (t == 0) {
    float H = red[0] + red[1] + red[2] + red[3];
    *out_perp = expf(H);
    double m = (sums[0] + sums[1]) / (double)((long long)NROWS * DIM);
    *out_loss = (float)(1.25 * m);
  }
}

extern "C" void kernel_launch(void* const* d_in, const int* in_sizes, int n_in,
                              void* d_out, int out_size, void* d_ws, size_t ws_size,
                              hipStream_t stream) {
  const float* X = (const float*)d_in[0];
  const float* W = (const float*)d_in[1];
  float* out = (float*)d_out;
  char* ws = (char*)d_ws;

  float* out_loss = out;                     // [0]
  float* out_perp = out + 1 + NROWS * DIM;   // [33554433]
  float* encf     = out + 2 + NROWS * DIM;   // [33554434 ..), 16B-aligned

  short8* WhT8   = (short8*)ws;                        // 1 MB
  float*  wnorm  = (float*)(ws + (1040u << 10));       // 4 KB
  int*    counts = (int*)(ws + (1040u << 10) + 4096);  // 4 KB
  double* sums   = (double*)(ws + (1040u << 10) + 8192); // [0]=sumX2 [1]=sumS

  wprep_kernel<<<KC / 4, 256, 0, stream>>>(W, WhT8, wnorm, counts, sums);
  mm_kernel<<<NROWS / 128, 256, 0, stream>>>(X, W, (const u16*)WhT8, wnorm,
                                             counts, sums, out, encf);
  finalize_kernel<<<1, 256, 0, stream>>>(counts, sums, out_loss, out_perp);
}